// Round 2
// baseline (1545.731 us; speedup 1.0000x reference)
//
#include <hip/hip_runtime.h>
#include <math.h>

// DeepSeek V4 MLA sparse top-k attention, f32 SIMT baseline.
// T=512 tokens, H=64 heads, D=576, DV=512, TOPK=512, NKV=32768.
// One block per token: 1024 threads = 16 waves, each wave owns 4 heads.
// KV tile (32 rows x 576 f32) staged in LDS once per token, shared by all heads.
// Online (flash) softmax with attention sink folded in at the end.

#define T_TOK 512
#define NHEAD 64
#define DIM   576
#define DV    512
#define TOPK  512
#define KVB   32
#define D_PAD 588   // 588 % 32 = 12 -> score-phase row reads ~2-way max
#define QK_SCALE 0.0416666666666666643537020044012f  // 576^-0.5

__global__ __launch_bounds__(1024) void mla_sparse_attn_kernel(
    const float* __restrict__ q,      // [T, H, D]
    const float* __restrict__ kv,     // [NKV, D]
    const int*   __restrict__ topk,   // [T, TOPK]
    const float* __restrict__ sink,   // [H]
    float* __restrict__ out)          // [T, H, DV]
{
    __shared__ int   s_idx[TOPK];
    __shared__ float s_k[KVB][D_PAD];
    __shared__ float s_p[NHEAD][33];  // pad 33 -> (h*33+k)%32 conflict-free

    const int t    = blockIdx.x;
    const int tid  = threadIdx.x;
    const int wave = tid >> 6;        // 0..15
    const int lane = tid & 63;
    const int hloc = lane >> 4;       // 0..3
    const int h    = wave * 4 + hloc; // 0..63
    const int kk   = lane & 15;       // score: key slot; PV: dim slot

    // stage top-k indices for this token
    for (int i = tid; i < TOPK; i += 1024) s_idx[i] = topk[t * TOPK + i];

    float m_run = -INFINITY;
    float l_run = 0.0f;
    float O[8][4];
    #pragma unroll
    for (int i = 0; i < 8; ++i) {
        #pragma unroll
        for (int j = 0; j < 4; ++j) O[i][j] = 0.0f;
    }

    const float4* q4 = reinterpret_cast<const float4*>(q + ((size_t)t * NHEAD + h) * DIM);

    for (int tile = 0; tile < TOPK / KVB; ++tile) {
        __syncthreads();  // also protects s_idx on first iter, s_k reuse after PV
        // ---- gather KVB rows into LDS (f32, coalesced float4) ----
        const int kbase = tile * KVB;
        for (int fid = tid; fid < KVB * 144; fid += 1024) {
            const int row = fid / 144;
            const int c4  = fid - row * 144;
            int idx = s_idx[kbase + row];
            if (idx < 0) idx = 0;  // masked later via -inf score
            const float4 v = reinterpret_cast<const float4*>(kv + (size_t)idx * DIM)[c4];
            *reinterpret_cast<float4*>(&s_k[row][c4 * 4]) = v;
        }
        __syncthreads();

        // ---- scores: each lane does 2 full 576-dim dots (keys kk, kk+16) ----
        float sc[2];
        #pragma unroll
        for (int r = 0; r < 2; ++r) {
            const int kl = kk + 16 * r;
            const float4* krow = reinterpret_cast<const float4*>(&s_k[kl][0]);
            float acc = 0.0f;
            #pragma unroll 8
            for (int d4 = 0; d4 < 144; ++d4) {
                const float4 kvv = krow[d4];
                const float4 qv  = q4[d4];   // broadcast within 16-lane group
                acc += qv.x * kvv.x;
                acc += qv.y * kvv.y;
                acc += qv.z * kvv.z;
                acc += qv.w * kvv.w;
            }
            float s = acc * QK_SCALE;
            if (s_idx[kbase + kl] < 0) s = -INFINITY;
            sc[r] = s;
        }

        // ---- online softmax update (per 16-lane head group) ----
        float tmax = fmaxf(sc[0], sc[1]);
        #pragma unroll
        for (int off = 1; off < 16; off <<= 1)
            tmax = fmaxf(tmax, __shfl_xor(tmax, off, 16));
        const float m_new = fmaxf(m_run, tmax);
        const float scale = (m_run == m_new) ? 1.0f : __expf(m_run - m_new);
        const float p0 = __expf(sc[0] - m_new);
        const float p1 = __expf(sc[1] - m_new);
        float psum = p0 + p1;
        #pragma unroll
        for (int off = 1; off < 16; off <<= 1)
            psum += __shfl_xor(psum, off, 16);
        l_run = l_run * scale + psum;
        if (scale != 1.0f) {
            #pragma unroll
            for (int i = 0; i < 8; ++i) {
                #pragma unroll
                for (int j = 0; j < 4; ++j) O[i][j] *= scale;
            }
        }
        m_run = m_new;
        s_p[h][kk]      = p0;   // intra-wave produce/consume; no barrier needed
        s_p[h][kk + 16] = p1;

        // ---- PV: lane owns dims {kk*4 + 64*i + j}, i<8, j<4 (covers [0,512)) ----
        for (int k = 0; k < KVB; ++k) {
            const float p = s_p[h][k];  // broadcast within head group
            const float* vrow = &s_k[k][0];
            #pragma unroll
            for (int i = 0; i < 8; ++i) {
                const float4 vv = *reinterpret_cast<const float4*>(&vrow[kk * 4 + 64 * i]);
                O[i][0] += p * vv.x;
                O[i][1] += p * vv.y;
                O[i][2] += p * vv.z;
                O[i][3] += p * vv.w;
            }
        }
    }

    // ---- finalize with attention sink ----
    const float snk = sink[h];
    const float M   = fmaxf(m_run, snk);
    const float ef  = __expf(m_run - M);
    const float denom = l_run * ef + __expf(snk - M);
    const float f = ef / denom;

    float* orow = out + ((size_t)t * NHEAD + h) * DV;
    #pragma unroll
    for (int i = 0; i < 8; ++i) {
        float4 vv;
        vv.x = O[i][0] * f;
        vv.y = O[i][1] * f;
        vv.z = O[i][2] * f;
        vv.w = O[i][3] * f;
        *reinterpret_cast<float4*>(&orow[kk * 4 + 64 * i]) = vv;
    }
}

extern "C" void kernel_launch(void* const* d_in, const int* in_sizes, int n_in,
                              void* d_out, int out_size, void* d_ws, size_t ws_size,
                              hipStream_t stream) {
    const float* q    = (const float*)d_in[0];
    const float* kv   = (const float*)d_in[1];
    const int*   topk = (const int*)d_in[2];
    const float* sink = (const float*)d_in[3];
    float* out = (float*)d_out;

    dim3 grid(T_TOK);
    dim3 block(1024);
    mla_sparse_attn_kernel<<<grid, block, 0, stream>>>(q, kv, topk, sink, out);
}